// Round 11
// baseline (340.766 us; speedup 1.0000x reference)
//
#include <hip/hip_runtime.h>
#include <hip/hip_bf16.h>
#include <math.h>

// ---------------------------------------------------------------------------
// InfomaxEncoder, round 11:
//  - edge: XW gathers software-pipelined ONE FULL TILE ahead (col already
//    known 2 ahead) -> gather latency hidden behind tile t's B-gen+MFMA+silu.
//    Double-buffered gx (+16 VGPR, no launch_bounds cap so no spill possible).
//  - everything else as round 10 (bf16 XW/S, LDS A-frags + anti-LICM, grux
//    32-atom MFMA blocks, no-atomic ln/pool, fused prep).
// Factorizations (exact): XW = X@W1_x + b1; S = segsum silu(XW[col] + rbf@W1r)
// over sorted rows; gi = S@Wc + deg*P + b_ih, Wc = W2@W_ih, P = b2@W_ih.
// ---------------------------------------------------------------------------

#define HH 128
#define RR 50
#define LL 4
#define L2E 1.4426950408889634f

typedef __attribute__((ext_vector_type(8))) short short8;
typedef __attribute__((ext_vector_type(4))) float floatx4;

__device__ __forceinline__ unsigned short f2bf(float f) {
    unsigned u = __float_as_uint(f);
    unsigned r = (u + 0x7fffu + ((u >> 16) & 1u)) >> 16;
    return (unsigned short)r;
}
// pack two floats to packed bf16 (lo|hi<<16), round-half-up via +0x8000 + v_perm
__device__ __forceinline__ unsigned pack_bf2(float lo, float hi) {
    unsigned u0 = __float_as_uint(lo) + 0x8000u;
    unsigned u1 = __float_as_uint(hi) + 0x8000u;
    return __builtin_amdgcn_perm(u1, u0, 0x07060302);
}
__device__ __forceinline__ float fast_sigmoid(float x) {
    return __builtin_amdgcn_rcpf(1.f + __builtin_amdgcn_exp2f(x * (-L2E)));
}
__device__ __forceinline__ float fast_tanh(float x) {
    x = fminf(fmaxf(x, -15.f), 15.f);
    float t = __builtin_amdgcn_exp2f(x * (2.f * L2E));
    return (t - 1.f) * __builtin_amdgcn_rcpf(t + 1.f);
}
__device__ __forceinline__ int imin(int a, int b) { return a < b ? a : b; }

// ---------------------------------------------------------------------------
// Fused one-time prep: initX | rowptr/bptr | dist | W1rTf | W1xT | WcT | P
// ---------------------------------------------------------------------------
__global__ __launch_bounds__(256) void prep_kernel(
    const int* __restrict__ an, const float* __restrict__ emb,
    float* __restrict__ X,
    const float* __restrict__ pos, const int* __restrict__ erow,
    const int* __restrict__ ecol, float* __restrict__ dist,
    int* __restrict__ rowptr, int* __restrict__ bptr,
    const int* __restrict__ batch,
    const float* __restrict__ W1, unsigned short* __restrict__ W1rT,
    unsigned short* __restrict__ W1xT,
    const float* __restrict__ W2, const float* __restrict__ Wih,
    unsigned short* __restrict__ WcT,
    const float* __restrict__ b2, float* __restrict__ P,
    int N, int E, int M)
{
    int gidx = blockIdx.x * 256 + threadIdx.x;
    int c0 = N * HH;
    if (gidx < c0) {                       // initX
        int i = gidx >> 7, n = gidx & 127;
        int z = an[i];
        z = z < 0 ? 0 : (z > 99 ? 99 : z);
        X[gidx] = emb[z * HH + n];
        return;
    }
    gidx -= c0;
    int PT = E > N ? E : N;
    if (gidx < PT) {                       // rowptr + bptr
        int i = gidx;
        if (i < E) {
            int rc = erow[i];
            int rp = (i > 0) ? erow[i - 1] : -1;
            for (int r = rp + 1; r <= rc; ++r) rowptr[r] = i;
            if (i == E - 1)
                for (int r = rc + 1; r <= N; ++r) rowptr[r] = E;
        }
        if (i < N) {
            int bc = batch[i];
            int bp = (i > 0) ? batch[i - 1] : -1;
            for (int m = bp + 1; m <= bc; ++m) bptr[m] = i;
            if (i == N - 1)
                for (int m = bc + 1; m <= M; ++m) bptr[m] = N;
        }
        return;
    }
    gidx -= PT;
    if (gidx < E) {                        // dist
        int e = gidx;
        int r = erow[e], c = ecol[e];
        float dx = pos[r * 3 + 0] - pos[c * 3 + 0];
        float dy = pos[r * 3 + 1] - pos[c * 3 + 1];
        float dz = pos[r * 3 + 2] - pos[c * 3 + 2];
        dist[e] = sqrtf(dx * dx + dy * dy + dz * dz);
        return;
    }
    gidx -= E;
    if (gidx < LL * HH * 64) {             // W1rTf frag-major
        int l = gidx >> 13, rem = gidx & 8191;
        int f = rem >> 9, lane2 = (rem >> 3) & 63, j = rem & 7;
        int nt = f >> 1, h = f & 1;
        int n = nt * 16 + (lane2 & 15);
        int k = h * 32 + (lane2 >> 4) * 8 + j;
        float v = (k < RR) ? W1[((size_t)l * 178 + 128 + k) * HH + n] : 0.f;
        W1rT[gidx] = f2bf(v);
        return;
    }
    gidx -= LL * HH * 64;
    if (gidx < LL * HH * HH) {             // W1xT[l][n][k] = W1[l][k][n]
        int l = gidx >> 14, rem = gidx & 16383, n = rem >> 7, k = rem & 127;
        W1xT[gidx] = f2bf(W1[((size_t)l * 178 + k) * HH + n]);
        return;
    }
    gidx -= LL * HH * HH;
    if (gidx < LL * HH * 384) {            // WcT[l][j][i] = sum_k W2[l][i][k]Wih[l][k][j]
        int l = gidx / (HH * 384), rem = gidx % (HH * 384);
        int i = rem / 384, j = rem % 384;
        const float* w2row = W2 + ((size_t)l * HH + i) * HH;
        const float* wih = Wih + (size_t)l * HH * 384;
        float acc = 0.f;
#pragma unroll 4
        for (int k = 0; k < HH; ++k)
            acc = fmaf(w2row[k], wih[(size_t)k * 384 + j], acc);
        WcT[((size_t)l * 384 + j) * HH + i] = f2bf(acc);
        return;
    }
    gidx -= LL * HH * 384;
    if (gidx < LL * 384) {                 // P[l][j] = sum_k b2[l][k]Wih[l][k][j]
        int l = gidx / 384, j = gidx % 384;
        const float* b2l = b2 + (size_t)l * HH;
        const float* wih = Wih + (size_t)l * HH * 384;
        float acc = 0.f;
#pragma unroll 4
        for (int k = 0; k < HH; ++k)
            acc = fmaf(b2l[k], wih[(size_t)k * 384 + j], acc);
        P[gidx] = acc;
    }
}

// XW = X @ W1_x + b1 (layer 0 only; later layers fused into grux_mfma)
#define XAB 32
__global__ __launch_bounds__(256) void xw_kernel(
    const float* __restrict__ X, const float* __restrict__ W,
    const float* __restrict__ bias, unsigned short* __restrict__ XWb, int N)
{
    __shared__ __align__(16) float A[XAB][HH];
    int tid = threadIdx.x;
    int abase = blockIdx.x * XAB;
    for (int idx = tid; idx < XAB * HH; idx += 256) {
        int a = idx >> 7, k = idx & 127;
        A[a][k] = (abase + a < N) ? X[(size_t)(abase + a) * HH + k] : 0.f;
    }
    __syncthreads();
    int n = tid & 127, s = tid >> 7;
    float acc[16];
#pragma unroll
    for (int i = 0; i < 16; ++i) acc[i] = 0.f;
    for (int kc = 0; kc < 32; ++kc) {
        float w0 = W[(4 * kc + 0) * HH + n];
        float w1 = W[(4 * kc + 1) * HH + n];
        float w2 = W[(4 * kc + 2) * HH + n];
        float w3 = W[(4 * kc + 3) * HH + n];
#pragma unroll
        for (int i = 0; i < 16; ++i) {
            float4 av = *(const float4*)&A[s * 16 + i][4 * kc];
            acc[i] = fmaf(av.x, w0, acc[i]);
            acc[i] = fmaf(av.y, w1, acc[i]);
            acc[i] = fmaf(av.z, w2, acc[i]);
            acc[i] = fmaf(av.w, w3, acc[i]);
        }
    }
    float b = bias[n];
#pragma unroll
    for (int i = 0; i < 16; ++i) {
        int a = abase + s * 16 + i;
        if (a < N) XWb[(size_t)a * HH + n] = f2bf(acc[i] + b);
    }
}

// ---------------------------------------------------------------------------
// Edge pass: A-frags in LDS (anti-LICM), 1 atom/wave.
// Pipeline: col known 2 tiles ahead; gx gathers for tile t+1 issued during
// tile t (double-buffered) -> gather latency off the critical path.
// ---------------------------------------------------------------------------
__global__ __launch_bounds__(256) void edge_mfma_kernel(
    const unsigned short* __restrict__ XWb, const unsigned short* __restrict__ W1rTf,
    const float* __restrict__ dist, const int* __restrict__ rowptr,
    const int* __restrict__ ecol, unsigned short* __restrict__ Sbf,
    int N, int nwaves)
{
    __shared__ __align__(16) unsigned short W1s[8192];   // 16 frags x 64 lanes x 8
    int tid = threadIdx.x;
    {
        const uint4* src = (const uint4*)W1rTf;
        uint4* dst = (uint4*)W1s;
#pragma unroll
        for (int i = 0; i < 4; ++i) dst[tid + i * 256] = src[tid + i * 256];
    }
    __syncthreads();

    int wid = (blockIdx.x << 2) + (tid >> 6);
    int lane = tid & 63;
    int c = lane & 15, q = lane >> 4;

    const float stepc = 5.0f / 49.0f;
    const float negc = -50.f * L2E;        // exp(-50 t^2) = exp2(negc*t^2)
    float kqs = (float)(q << 3) * stepc;

    for (int a = wid; a < N; a += nwaves) {
        int es = rowptr[a], ee = rowptr[a + 1];
        float acc[8][4];
#pragma unroll
        for (int nt = 0; nt < 8; ++nt)
#pragma unroll
            for (int r = 0; r < 4; ++r) acc[nt][r] = 0.f;

        if (es < ee) {
            int last = ee - 1;
            // tile 0: immediate gather
            int e0 = imin(es + c, last);
            int colg = ecol[e0];
            float dcur = dist[e0];
            // tile 1 col (ready for gxB issue at iter 0), tile 1 dist
            int e1 = imin(es + 16 + c, last);
            int colA = ecol[e1];
            float dnxt = dist[e1];
            // tile 2 col
            int e2 = imin(es + 32 + c, last);
            int colB = ecol[e2];

            uint2 gxA[8];
            {
                const unsigned short* xwrow = XWb + (size_t)colg * HH;
#pragma unroll
                for (int nt = 0; nt < 8; ++nt)
                    gxA[nt] = *(const uint2*)&xwrow[nt * 16 + (q << 2)];
            }

            for (int eb = es; eb < ee; eb += 16) {
                // issue NEXT tile's gathers first (latency overlapped below)
                uint2 gxB[8];
                {
                    const unsigned short* xwrow = XWb + (size_t)colA * HH;
#pragma unroll
                    for (int nt = 0; nt < 8; ++nt)
                        gxB[nt] = *(const uint2*)&xwrow[nt * 16 + (q << 2)];
                }
                colA = colB;
                int e3 = imin(eb + 48 + c, last);
                colB = ecol[e3];

                float d_t = dcur;
                dcur = dnxt;
                int e4 = imin(eb + 32 + c, last);
                dnxt = dist[e4];

                // B-gen: k = h*32 + q*8 + j
                float dq0 = d_t - kqs;
                float dq1 = dq0 - 32.f * stepc;
                union { unsigned u[4]; short8 s; } ub0, ub1;
#pragma unroll
                for (int p = 0; p < 4; ++p) {
                    float t0 = dq0 - (float)(2 * p) * stepc;
                    float t1 = dq0 - (float)(2 * p + 1) * stepc;
                    float e0f = __builtin_amdgcn_exp2f(negc * t0 * t0);
                    float e1f = __builtin_amdgcn_exp2f(negc * t1 * t1);
                    ub0.u[p] = pack_bf2(e0f, e1f);
                    float t2 = dq1 - (float)(2 * p) * stepc;
                    float t3 = dq1 - (float)(2 * p + 1) * stepc;
                    float e2f = __builtin_amdgcn_exp2f(negc * t2 * t2);
                    float e3f = __builtin_amdgcn_exp2f(negc * t3 * t3);
                    ub1.u[p] = pack_bf2(e2f, e3f);
                }
                short8 B0 = ub0.s, B1 = ub1.s;
                float msk = ((eb + c) < ee) ? 1.f : 0.f;

                // Anti-LICM: opaque LDS offset per tile -> ds_reads stay in
                // loop (not hoisted into 64 VGPRs; r7/r8 spill lesson).
                unsigned wbyte = (unsigned)(lane * 16);
                asm volatile("" : "+v"(wbyte));
                const char* Wlp = (const char*)W1s + wbyte;

#pragma unroll
                for (int nt = 0; nt < 8; ++nt) {
                    short8 A0 = *(const short8*)(Wlp + (nt * 2 + 0) * 1024);
                    short8 A1 = *(const short8*)(Wlp + (nt * 2 + 1) * 1024);
                    floatx4 C;
                    C[0] = __uint_as_float(gxA[nt].x << 16);
                    C[1] = __uint_as_float(gxA[nt].x & 0xffff0000u);
                    C[2] = __uint_as_float(gxA[nt].y << 16);
                    C[3] = __uint_as_float(gxA[nt].y & 0xffff0000u);
                    C = __builtin_amdgcn_mfma_f32_16x16x32_bf16(A0, B0, C, 0, 0, 0);
                    C = __builtin_amdgcn_mfma_f32_16x16x32_bf16(A1, B1, C, 0, 0, 0);
#pragma unroll
                    for (int r = 0; r < 4; ++r) {
                        float h = C[r];
                        float v = h * fast_sigmoid(h);   // silu
                        acc[nt][r] = fmaf(v, msk, acc[nt][r]);
                    }
                }
                // rotate gather buffer
#pragma unroll
                for (int nt = 0; nt < 8; ++nt) gxA[nt] = gxB[nt];
            }
        }

        // Index-splitting butterfly over the 16 edge-classes (c bits).
        int b3 = (c >> 3) & 1, b0 = c & 1, b1 = (c >> 1) & 1, b2 = (c >> 2) & 1;
        float s16[8][2];
#pragma unroll
        for (int t = 0; t < 8; ++t)
#pragma unroll
            for (int p = 0; p < 2; ++p) {
                float keep = b3 ? acc[t][2 + p] : acc[t][p];
                float send = b3 ? acc[t][p] : acc[t][2 + p];
                s16[t][p] = keep + __shfl_xor(send, 8, 64);
            }
        float s8[4][2];
#pragma unroll
        for (int t = 0; t < 4; ++t)
#pragma unroll
            for (int p = 0; p < 2; ++p) {
                float keep = b0 ? s16[2 * t + 1][p] : s16[2 * t][p];
                float send = b0 ? s16[2 * t][p] : s16[2 * t + 1][p];
                s8[t][p] = keep + __shfl_xor(send, 1, 64);
            }
        float s4[2][2];
#pragma unroll
        for (int u = 0; u < 2; ++u)
#pragma unroll
            for (int p = 0; p < 2; ++p) {
                float keep = b1 ? s8[2 * u + 1][p] : s8[2 * u][p];
                float send = b1 ? s8[2 * u][p] : s8[2 * u + 1][p];
                s4[u][p] = keep + __shfl_xor(send, 2, 64);
            }
        float s2[2];
#pragma unroll
        for (int p = 0; p < 2; ++p) {
            float keep = b2 ? s4[1][p] : s4[0][p];
            float send = b2 ? s4[0][p] : s4[1][p];
            s2[p] = keep + __shfl_xor(send, 4, 64);
        }
        // bf16 store (grux rounds at staging anyway -> identical)
        unsigned pk = pack_bf2(s2[0], s2[1]);
        *(unsigned*)&Sbf[(size_t)a * HH + (c & 7) * 16 + (q << 2) + (b3 << 1)] = pk;
    }
}

// ---------------------------------------------------------------------------
// GRU via MFMA + fused next-layer XW. Block = 32 atoms (2 sub-tiles), 4 waves.
// S arrives bf16 (raw copy to LDS). LDS pad 136 shorts.
// ---------------------------------------------------------------------------
#define GA 32
__global__ __launch_bounds__(256) void grux_mfma_kernel(
    const unsigned short* __restrict__ Sbf, const unsigned short* __restrict__ WcT,
    const float* __restrict__ P, const float* __restrict__ bih,
    const float* __restrict__ bhh, const int* __restrict__ rowptr,
    float* __restrict__ X, int N,
    const unsigned short* __restrict__ W1xT, const float* __restrict__ b1next,
    unsigned short* __restrict__ XWb, int do_xw)
{
    __shared__ __align__(16) unsigned short Sb[GA][136];
    __shared__ __align__(16) unsigned short Xb[GA][136];
    int tid = threadIdx.x;
    int abase = blockIdx.x * GA;
    int w = tid >> 6, lane = tid & 63, c = lane & 15, q = lane >> 4;

    // hoisted epilogue operands
    float pn[2][3], bi[2][3], bh[2][3], deg[2][4];
#pragma unroll
    for (int t = 0; t < 2; ++t) {
        int n = w * 32 + t * 16 + c;
#pragma unroll
        for (int g = 0; g < 3; ++g) {
            pn[t][g] = P[g * 128 + n];
            bi[t][g] = bih[g * 128 + n];
            bh[t][g] = bhh[g * 128 + n];
        }
    }
#pragma unroll
    for (int sub = 0; sub < 2; ++sub)
#pragma unroll
        for (int r = 0; r < 4; ++r) {
            int a = abase + sub * 16 + q * 4 + r;
            deg[sub][r] = (a < N) ? (float)(rowptr[a + 1] - rowptr[a]) : 0.f;
        }

    // stage bf16 S tile -> LDS (raw copy)
    {
        int a = tid >> 3, ch = tid & 7;
        int aa = abase + a; if (aa >= N) aa = N - 1;
        const uint4* src = (const uint4*)(Sbf + (size_t)aa * HH + ch * 16);
        uint4 v0 = src[0];
        uint4 v1 = src[1];
        uint4* dst = (uint4*)&Sb[a][ch * 16];
        dst[0] = v0;
        dst[1] = v1;
    }
    __syncthreads();

    floatx4 Cg[3][2][2];   // [gate][t][sub]
#pragma unroll
    for (int g = 0; g < 3; ++g)
#pragma unroll
        for (int t = 0; t < 2; ++t)
#pragma unroll
            for (int sub = 0; sub < 2; ++sub)
                Cg[g][t][sub] = floatx4{0.f, 0.f, 0.f, 0.f};

#pragma unroll
    for (int kt = 0; kt < 4; ++kt) {
        short8 A0 = *(const short8*)&Sb[c][kt * 32 + q * 8];
        short8 A1 = *(const short8*)&Sb[16 + c][kt * 32 + q * 8];
#pragma unroll
        for (int g = 0; g < 3; ++g)
#pragma unroll
            for (int t = 0; t < 2; ++t) {
                int nrow = g * 128 + w * 32 + t * 16 + c;
                short8 B = *(const short8*)&WcT[(size_t)nrow * HH + kt * 32 + q * 8];
                Cg[g][t][0] = __builtin_amdgcn_mfma_f32_16x16x32_bf16(A0, B, Cg[g][t][0], 0, 0, 0);
                Cg[g][t][1] = __builtin_amdgcn_mfma_f32_16x16x32_bf16(A1, B, Cg[g][t][1], 0, 0, 0);
            }
    }

#pragma unroll
    for (int sub = 0; sub < 2; ++sub)
#pragma unroll
        for (int r = 0; r < 4; ++r) {
            int am = sub * 16 + q * 4 + r;
            int a = abase + am;
            bool ok = a < N;
#pragma unroll
            for (int t = 0; t < 2; ++t) {
                int n = w * 32 + t * 16 + c;
                float g0 = Cg[0][t][sub][r] + deg[sub][r] * pn[t][0] + bi[t][0];
                float g1 = Cg[1][t][sub][r] + deg[sub][r] * pn[t][1] + bi[t][1];
                float g2 = Cg[2][t][sub][r] + deg[sub][r] * pn[t][2] + bi[t][2];
                float rr = fast_sigmoid(g0 + bh[t][0]);
                float zz = fast_sigmoid(g1 + bh[t][1]);
                float nn = fast_tanh(g2 + rr * bh[t][2]);
                float xv = 0.f;
                if (ok) {
                    xv = X[(size_t)a * HH + n] + (1.f - zz) * nn;
                    X[(size_t)a * HH + n] = xv;
                }
                Xb[am][n] = f2bf(xv);
            }
        }

    if (!do_xw) return;
    __syncthreads();

    floatx4 Cx[2][2];
#pragma unroll
    for (int t = 0; t < 2; ++t)
#pragma unroll
        for (int sub = 0; sub < 2; ++sub)
            Cx[t][sub] = floatx4{0.f, 0.f, 0.f, 0.f};
#pragma unroll
    for (int kt = 0; kt < 4; ++kt) {
        short8 A0 = *(const short8*)&Xb[c][kt * 32 + q * 8];
        short8 A1 = *(const short8*)&Xb[16 + c][kt * 32 + q * 8];
#pragma unroll
        for (int t = 0; t < 2; ++t) {
            int nrow = w * 32 + t * 16 + c;
            short8 B = *(const short8*)&W1xT[(size_t)nrow * HH + kt * 32 + q * 8];
            Cx[t][0] = __builtin_amdgcn_mfma_f32_16x16x32_bf16(A0, B, Cx[t][0], 0, 0, 0);
            Cx[t][1] = __builtin_amdgcn_mfma_f32_16x16x32_bf16(A1, B, Cx[t][1], 0, 0, 0);
        }
    }
#pragma unroll
    for (int sub = 0; sub < 2; ++sub)
#pragma unroll
        for (int r = 0; r < 4; ++r) {
            int a = abase + sub * 16 + q * 4 + r;
            if (a >= N) continue;
#pragma unroll
            for (int t = 0; t < 2; ++t) {
                int n = w * 32 + t * 16 + c;
                XWb[(size_t)a * HH + n] = f2bf(Cx[t][sub][r] + b1next[n]);
            }
        }
}

// LayerNorm -> d_out x region (no atomics)
__global__ __launch_bounds__(256) void ln_kernel(
    const float* __restrict__ X, const float* __restrict__ g,
    const float* __restrict__ b, float* __restrict__ out, int N)
{
    int a = blockIdx.x * 4 + (threadIdx.x >> 6);
    int lane = threadIdx.x & 63;
    if (a >= N) return;
    float v0 = X[(size_t)a * HH + lane];
    float v1 = X[(size_t)a * HH + 64 + lane];
    float sm = v0 + v1;
    for (int off = 32; off > 0; off >>= 1) sm += __shfl_xor(sm, off, 64);
    float mu = sm * (1.f / 128.f);
    float d0 = v0 - mu, d1 = v1 - mu;
    float vq = d0 * d0 + d1 * d1;
    for (int off = 32; off > 0; off >>= 1) vq += __shfl_xor(vq, off, 64);
    float inv = rsqrtf(vq * (1.f / 128.f) + 1e-5f);
    out[(size_t)a * HH + lane] = d0 * inv * g[lane] + b[lane];
    out[(size_t)a * HH + 64 + lane] = d1 * inv * g[64 + lane] + b[64 + lane];
}

// Block-per-molecule mean pool over sorted batch segments.
__global__ __launch_bounds__(256) void pool_kernel(
    const float* __restrict__ outx, const int* __restrict__ bptr,
    float* __restrict__ outg)
{
    __shared__ float sm[256];
    int m = blockIdx.x, t = threadIdx.x;
    int n = t & 127, s = t >> 7;
    int a0 = bptr[m], a1 = bptr[m + 1];
    float acc = 0.f;
    for (int a = a0 + s; a < a1; a += 2)
        acc += outx[(size_t)a * HH + n];
    sm[t] = acc;
    __syncthreads();
    if (t < 128) {
        float cnt = (float)(a1 - a0);
        outg[(size_t)m * HH + t] = (sm[t] + sm[t + 128]) / fmaxf(cnt, 1.f);
    }
}

extern "C" void kernel_launch(void* const* d_in, const int* in_sizes, int n_in,
                              void* d_out, int out_size, void* d_ws, size_t ws_size,
                              hipStream_t stream)
{
    const int*   an   = (const int*)d_in[0];
    const float* pos  = (const float*)d_in[1];
    const int*   bat  = (const int*)d_in[2];
    const int*   eidx = (const int*)d_in[3];
    const float* emb  = (const float*)d_in[4];
    const float* W1   = (const float*)d_in[5];
    const float* b1   = (const float*)d_in[6];
    const float* W2   = (const float*)d_in[7];
    const float* b2   = (const float*)d_in[8];
    const float* Wih  = (const float*)d_in[9];
    const float* bih  = (const float*)d_in[10];
    const float* bhh  = (const float*)d_in[11];
    const float* lng  = (const float*)d_in[12];
    const float* lnb  = (const float*)d_in[13];

    int N = in_sizes[0];
    int E = in_sizes[3] / 2;
    int M = out_size / HH - N;
    const int* erow = eidx;
    const int* ecol = eidx + E;

    float* ws   = (float*)d_ws;
    size_t off = 0;
    float* X    = ws + off; off += (size_t)N * HH;
    unsigned short* Sbf = (unsigned short*)(ws + off); off += (size_t)N * HH / 2;
    unsigned short* XWb = (unsigned short*)(ws + off); off += (size_t)N * HH / 2;
    float* P    = ws + off; off += LL * 384;
    float* dist = ws + off; off += E;
    int* rowptr = (int*)(ws + off); off += N + 1;
    int* bptr   = (int*)(ws + off); off += M + 1;
    off = (off + 3) & ~(size_t)3;
    unsigned short* W1rT = (unsigned short*)(ws + off); off += (size_t)LL * HH * 32;
    unsigned short* W1xT = (unsigned short*)(ws + off); off += (size_t)LL * HH * 64;
    unsigned short* WcT  = (unsigned short*)(ws + off); off += (size_t)LL * 384 * 64;

    float* outx = (float*)d_out;
    float* outg = outx + (size_t)N * HH;

    int PT = (E > N ? E : N);
    long total = (long)N * HH + PT + E + LL * HH * 64 + LL * HH * HH
               + LL * HH * 384 + LL * 384;
    int prep_blocks = (int)((total + 255) / 256);

    prep_kernel<<<prep_blocks, 256, 0, stream>>>(
        an, emb, X, pos, erow, ecol, dist, rowptr, bptr, bat,
        W1, W1rT, W1xT, W2, Wih, WcT, b2, P, N, E, M);

    xw_kernel<<<(N + XAB - 1) / XAB, 256, 0, stream>>>(X, W1, b1, XWb, N);

    int eblocks = (N + 3) / 4;           // one atom per wave
    int nwaves = eblocks * 4;
    int grux_blocks = (N + GA - 1) / GA;
    for (int l = 0; l < LL; ++l) {
        edge_mfma_kernel<<<eblocks, 256, 0, stream>>>(
            XWb, W1rT + (size_t)l * HH * 64, dist, rowptr, ecol, Sbf, N, nwaves);
        int do_xw = (l < LL - 1) ? 1 : 0;
        int ln = (l + 1 < LL) ? l + 1 : l;
        grux_mfma_kernel<<<grux_blocks, 256, 0, stream>>>(
            Sbf, WcT + (size_t)l * 384 * HH, P + l * 384,
            bih + l * 384, bhh + l * 384, rowptr, X, N,
            W1xT + (size_t)ln * HH * HH, b1 + (size_t)ln * HH, XWb, do_xw);
    }

    ln_kernel<<<(N + 3) / 4, 256, 0, stream>>>(X, lng, lnb, outx, N);
    pool_kernel<<<M, 256, 0, stream>>>(outx, bptr, outg);
}

// Round 12
// 314.527 us; speedup vs baseline: 1.0834x; 1.0834x over previous
//
#include <hip/hip_runtime.h>
#include <hip/hip_bf16.h>
#include <math.h>

// ---------------------------------------------------------------------------
// InfomaxEncoder, round 12:
//  - edge: atom split across 2 WAVES (n-halves of 64) -> acc[4][4]=16 VGPR,
//    ~70 total -> ~7 waves/SIMD and 2x wave count (20000). Gather reverted to
//    round-10 form (r11 explicit pipeline regressed: +VGPR > latency hidden).
//    New 4-ntile butterfly: c bits -> (r,t); one bf16 store per lane.
//  - ln+pool fused (block-per-molecule, 1024 thr): -1 launch, -5MB re-read.
//  - rest as round 10 (bf16 XW/S, LDS A-frags + anti-LICM, grux 32-atom MFMA).
// Factorizations (exact): XW = X@W1_x + b1; S = segsum silu(XW[col] + rbf@W1r)
// over sorted rows; gi = S@Wc + deg*P + b_ih, Wc = W2@W_ih, P = b2@W_ih.
// ---------------------------------------------------------------------------

#define HH 128
#define RR 50
#define LL 4
#define L2E 1.4426950408889634f

typedef __attribute__((ext_vector_type(8))) short short8;
typedef __attribute__((ext_vector_type(4))) float floatx4;

__device__ __forceinline__ unsigned short f2bf(float f) {
    unsigned u = __float_as_uint(f);
    unsigned r = (u + 0x7fffu + ((u >> 16) & 1u)) >> 16;
    return (unsigned short)r;
}
__device__ __forceinline__ unsigned pack_bf2(float lo, float hi) {
    unsigned u0 = __float_as_uint(lo) + 0x8000u;
    unsigned u1 = __float_as_uint(hi) + 0x8000u;
    return __builtin_amdgcn_perm(u1, u0, 0x07060302);
}
__device__ __forceinline__ float fast_sigmoid(float x) {
    return __builtin_amdgcn_rcpf(1.f + __builtin_amdgcn_exp2f(x * (-L2E)));
}
__device__ __forceinline__ float fast_tanh(float x) {
    x = fminf(fmaxf(x, -15.f), 15.f);
    float t = __builtin_amdgcn_exp2f(x * (2.f * L2E));
    return (t - 1.f) * __builtin_amdgcn_rcpf(t + 1.f);
}
__device__ __forceinline__ int imin(int a, int b) { return a < b ? a : b; }

// ---------------------------------------------------------------------------
// Fused one-time prep: initX | rowptr/bptr | dist | W1rTf | W1xT | WcT | P
// ---------------------------------------------------------------------------
__global__ __launch_bounds__(256) void prep_kernel(
    const int* __restrict__ an, const float* __restrict__ emb,
    float* __restrict__ X,
    const float* __restrict__ pos, const int* __restrict__ erow,
    const int* __restrict__ ecol, float* __restrict__ dist,
    int* __restrict__ rowptr, int* __restrict__ bptr,
    const int* __restrict__ batch,
    const float* __restrict__ W1, unsigned short* __restrict__ W1rT,
    unsigned short* __restrict__ W1xT,
    const float* __restrict__ W2, const float* __restrict__ Wih,
    unsigned short* __restrict__ WcT,
    const float* __restrict__ b2, float* __restrict__ P,
    int N, int E, int M)
{
    int gidx = blockIdx.x * 256 + threadIdx.x;
    int c0 = N * HH;
    if (gidx < c0) {                       // initX
        int i = gidx >> 7, n = gidx & 127;
        int z = an[i];
        z = z < 0 ? 0 : (z > 99 ? 99 : z);
        X[gidx] = emb[z * HH + n];
        return;
    }
    gidx -= c0;
    int PT = E > N ? E : N;
    if (gidx < PT) {                       // rowptr + bptr
        int i = gidx;
        if (i < E) {
            int rc = erow[i];
            int rp = (i > 0) ? erow[i - 1] : -1;
            for (int r = rp + 1; r <= rc; ++r) rowptr[r] = i;
            if (i == E - 1)
                for (int r = rc + 1; r <= N; ++r) rowptr[r] = E;
        }
        if (i < N) {
            int bc = batch[i];
            int bp = (i > 0) ? batch[i - 1] : -1;
            for (int m = bp + 1; m <= bc; ++m) bptr[m] = i;
            if (i == N - 1)
                for (int m = bc + 1; m <= M; ++m) bptr[m] = N;
        }
        return;
    }
    gidx -= PT;
    if (gidx < E) {                        // dist
        int e = gidx;
        int r = erow[e], c = ecol[e];
        float dx = pos[r * 3 + 0] - pos[c * 3 + 0];
        float dy = pos[r * 3 + 1] - pos[c * 3 + 1];
        float dz = pos[r * 3 + 2] - pos[c * 3 + 2];
        dist[e] = sqrtf(dx * dx + dy * dy + dz * dz);
        return;
    }
    gidx -= E;
    if (gidx < LL * HH * 64) {             // W1rTf frag-major
        int l = gidx >> 13, rem = gidx & 8191;
        int f = rem >> 9, lane2 = (rem >> 3) & 63, j = rem & 7;
        int nt = f >> 1, h = f & 1;
        int n = nt * 16 + (lane2 & 15);
        int k = h * 32 + (lane2 >> 4) * 8 + j;
        float v = (k < RR) ? W1[((size_t)l * 178 + 128 + k) * HH + n] : 0.f;
        W1rT[gidx] = f2bf(v);
        return;
    }
    gidx -= LL * HH * 64;
    if (gidx < LL * HH * HH) {             // W1xT[l][n][k] = W1[l][k][n]
        int l = gidx >> 14, rem = gidx & 16383, n = rem >> 7, k = rem & 127;
        W1xT[gidx] = f2bf(W1[((size_t)l * 178 + k) * HH + n]);
        return;
    }
    gidx -= LL * HH * HH;
    if (gidx < LL * HH * 384) {            // WcT[l][j][i] = sum_k W2[l][i][k]Wih[l][k][j]
        int l = gidx / (HH * 384), rem = gidx % (HH * 384);
        int i = rem / 384, j = rem % 384;
        const float* w2row = W2 + ((size_t)l * HH + i) * HH;
        const float* wih = Wih + (size_t)l * HH * 384;
        float acc = 0.f;
#pragma unroll 4
        for (int k = 0; k < HH; ++k)
            acc = fmaf(w2row[k], wih[(size_t)k * 384 + j], acc);
        WcT[((size_t)l * 384 + j) * HH + i] = f2bf(acc);
        return;
    }
    gidx -= LL * HH * 384;
    if (gidx < LL * 384) {                 // P[l][j] = sum_k b2[l][k]Wih[l][k][j]
        int l = gidx / 384, j = gidx % 384;
        const float* b2l = b2 + (size_t)l * HH;
        const float* wih = Wih + (size_t)l * HH * 384;
        float acc = 0.f;
#pragma unroll 4
        for (int k = 0; k < HH; ++k)
            acc = fmaf(b2l[k], wih[(size_t)k * 384 + j], acc);
        P[gidx] = acc;
    }
}

// XW = X @ W1_x + b1 (layer 0 only; later layers fused into grux_mfma)
#define XAB 32
__global__ __launch_bounds__(256) void xw_kernel(
    const float* __restrict__ X, const float* __restrict__ W,
    const float* __restrict__ bias, unsigned short* __restrict__ XWb, int N)
{
    __shared__ __align__(16) float A[XAB][HH];
    int tid = threadIdx.x;
    int abase = blockIdx.x * XAB;
    for (int idx = tid; idx < XAB * HH; idx += 256) {
        int a = idx >> 7, k = idx & 127;
        A[a][k] = (abase + a < N) ? X[(size_t)(abase + a) * HH + k] : 0.f;
    }
    __syncthreads();
    int n = tid & 127, s = tid >> 7;
    float acc[16];
#pragma unroll
    for (int i = 0; i < 16; ++i) acc[i] = 0.f;
    for (int kc = 0; kc < 32; ++kc) {
        float w0 = W[(4 * kc + 0) * HH + n];
        float w1 = W[(4 * kc + 1) * HH + n];
        float w2 = W[(4 * kc + 2) * HH + n];
        float w3 = W[(4 * kc + 3) * HH + n];
#pragma unroll
        for (int i = 0; i < 16; ++i) {
            float4 av = *(const float4*)&A[s * 16 + i][4 * kc];
            acc[i] = fmaf(av.x, w0, acc[i]);
            acc[i] = fmaf(av.y, w1, acc[i]);
            acc[i] = fmaf(av.z, w2, acc[i]);
            acc[i] = fmaf(av.w, w3, acc[i]);
        }
    }
    float b = bias[n];
#pragma unroll
    for (int i = 0; i < 16; ++i) {
        int a = abase + s * 16 + i;
        if (a < N) XWb[(size_t)a * HH + n] = f2bf(acc[i] + b);
    }
}

// ---------------------------------------------------------------------------
// Edge pass, half-split: wave handles (atom, n-half). acc[4][4] (16 VGPR).
// A-frags in LDS (anti-LICM), r10-style gather with 2-ahead col prefetch.
// Butterfly folds c's 4 bits -> (r,t); n = t*16+q*4+r within the half.
// ---------------------------------------------------------------------------
__global__ __launch_bounds__(256) void edge_mfma_kernel(
    const unsigned short* __restrict__ XWb, const unsigned short* __restrict__ W1rTf,
    const float* __restrict__ dist, const int* __restrict__ rowptr,
    const int* __restrict__ ecol, unsigned short* __restrict__ Sbf,
    int N, int nwaves)
{
    __shared__ __align__(16) unsigned short W1s[8192];   // 16 frags x 64 lanes x 8
    int tid = threadIdx.x;
    {
        const uint4* src = (const uint4*)W1rTf;
        uint4* dst = (uint4*)W1s;
#pragma unroll
        for (int i = 0; i < 4; ++i) dst[tid + i * 256] = src[tid + i * 256];
    }
    __syncthreads();

    int wid = (blockIdx.x << 2) + (tid >> 6);
    int lane = tid & 63;
    int c = lane & 15, q = lane >> 4;

    const float stepc = 5.0f / 49.0f;
    const float negc = -50.f * L2E;        // exp(-50 t^2) = exp2(negc*t^2)
    float kqs = (float)(q << 3) * stepc;

    int NW = 2 * N;
    for (int w = wid; w < NW; w += nwaves) {
        int a = w >> 1, h = w & 1;         // atom, n-half
        int es = rowptr[a], ee = rowptr[a + 1];
        float acc[4][4];
#pragma unroll
        for (int t = 0; t < 4; ++t)
#pragma unroll
            for (int r = 0; r < 4; ++r) acc[t][r] = 0.f;

        if (es < ee) {
            int last = ee - 1;
            int ce0 = imin(es + c, last);
            float dcur = dist[ce0];
            int colcur = ecol[ce0];
            int ce1 = imin(es + 16 + c, last);
            float dnxt = dist[ce1];
            int colnxt = ecol[ce1];

            for (int eb = es; eb < ee; eb += 16) {
                const unsigned short* xwrow = XWb + (size_t)colcur * HH + h * 64;
                uint2 gx[4];
#pragma unroll
                for (int t = 0; t < 4; ++t)
                    gx[t] = *(const uint2*)&xwrow[t * 16 + (q << 2)];

                float d_t = dcur;
                dcur = dnxt; colcur = colnxt;
                int ce2 = imin(eb + 32 + c, last);
                dnxt = dist[ce2];
                colnxt = ecol[ce2];

                // B-gen: k = hk*32 + q*8 + j (full k range, shared by halves)
                float dq0 = d_t - kqs;
                float dq1 = dq0 - 32.f * stepc;
                union { unsigned u[4]; short8 s; } ub0, ub1;
#pragma unroll
                for (int p = 0; p < 4; ++p) {
                    float t0 = dq0 - (float)(2 * p) * stepc;
                    float t1 = dq0 - (float)(2 * p + 1) * stepc;
                    float e0f = __builtin_amdgcn_exp2f(negc * t0 * t0);
                    float e1f = __builtin_amdgcn_exp2f(negc * t1 * t1);
                    ub0.u[p] = pack_bf2(e0f, e1f);
                    float t2 = dq1 - (float)(2 * p) * stepc;
                    float t3 = dq1 - (float)(2 * p + 1) * stepc;
                    float e2f = __builtin_amdgcn_exp2f(negc * t2 * t2);
                    float e3f = __builtin_amdgcn_exp2f(negc * t3 * t3);
                    ub1.u[p] = pack_bf2(e2f, e3f);
                }
                short8 B0 = ub0.s, B1 = ub1.s;
                float msk = ((eb + c) < ee) ? 1.f : 0.f;

                // Anti-LICM: opaque LDS offset so ds_reads stay per-tile
                // (not hoisted into 32 VGPRs; r7/r8 spill lesson).
                unsigned wbyte = (unsigned)(lane * 16);
                asm volatile("" : "+v"(wbyte));
                const char* Wlp = (const char*)W1s + wbyte;

#pragma unroll
                for (int t = 0; t < 4; ++t) {
                    int f0 = (h * 4 + t) * 2;
                    short8 A0 = *(const short8*)(Wlp + f0 * 1024);
                    short8 A1 = *(const short8*)(Wlp + (f0 + 1) * 1024);
                    floatx4 C;
                    C[0] = __uint_as_float(gx[t].x << 16);
                    C[1] = __uint_as_float(gx[t].x & 0xffff0000u);
                    C[2] = __uint_as_float(gx[t].y << 16);
                    C[3] = __uint_as_float(gx[t].y & 0xffff0000u);
                    C = __builtin_amdgcn_mfma_f32_16x16x32_bf16(A0, B0, C, 0, 0, 0);
                    C = __builtin_amdgcn_mfma_f32_16x16x32_bf16(A1, B1, C, 0, 0, 0);
#pragma unroll
                    for (int r = 0; r < 4; ++r) {
                        float hh = C[r];
                        float v = hh * fast_sigmoid(hh);   // silu
                        acc[t][r] = fmaf(v, msk, acc[t][r]);
                    }
                }
            }
        }

        // Butterfly: fold c bits (b0,b1 -> r ; b2,b3 -> t).
        int b0 = c & 1, b1 = (c >> 1) & 1, b2 = (c >> 2) & 1, b3 = (c >> 3) & 1;
        float s1[4][2];
#pragma unroll
        for (int t = 0; t < 4; ++t)
#pragma unroll
            for (int p = 0; p < 2; ++p) {
                float keep = b0 ? acc[t][2 * p + 1] : acc[t][2 * p];
                float send = b0 ? acc[t][2 * p] : acc[t][2 * p + 1];
                s1[t][p] = keep + __shfl_xor(send, 1, 64);
            }
        float s2[4];
#pragma unroll
        for (int t = 0; t < 4; ++t) {
            float keep = b1 ? s1[t][1] : s1[t][0];
            float send = b1 ? s1[t][0] : s1[t][1];
            s2[t] = keep + __shfl_xor(send, 2, 64);
        }
        float s3[2];
#pragma unroll
        for (int u = 0; u < 2; ++u) {
            float keep = b2 ? s2[2 * u + 1] : s2[2 * u];
            float send = b2 ? s2[2 * u] : s2[2 * u + 1];
            s3[u] = keep + __shfl_xor(send, 4, 64);
        }
        float keep = b3 ? s3[1] : s3[0];
        float send = b3 ? s3[0] : s3[1];
        float fin = keep + __shfl_xor(send, 8, 64);

        int t_fin = 2 * b3 + b2;
        int r_fin = 2 * b1 + b0;
        int n = t_fin * 16 + (q << 2) + r_fin;
        Sbf[(size_t)a * HH + h * 64 + n] = f2bf(fin);
    }
}

// ---------------------------------------------------------------------------
// GRU via MFMA + fused next-layer XW. Block = 32 atoms (2 sub-tiles), 4 waves.
// ---------------------------------------------------------------------------
#define GA 32
__global__ __launch_bounds__(256) void grux_mfma_kernel(
    const unsigned short* __restrict__ Sbf, const unsigned short* __restrict__ WcT,
    const float* __restrict__ P, const float* __restrict__ bih,
    const float* __restrict__ bhh, const int* __restrict__ rowptr,
    float* __restrict__ X, int N,
    const unsigned short* __restrict__ W1xT, const float* __restrict__ b1next,
    unsigned short* __restrict__ XWb, int do_xw)
{
    __shared__ __align__(16) unsigned short Sb[GA][136];
    __shared__ __align__(16) unsigned short Xb[GA][136];
    int tid = threadIdx.x;
    int abase = blockIdx.x * GA;
    int w = tid >> 6, lane = tid & 63, c = lane & 15, q = lane >> 4;

    float pn[2][3], bi[2][3], bh[2][3], deg[2][4];
#pragma unroll
    for (int t = 0; t < 2; ++t) {
        int n = w * 32 + t * 16 + c;
#pragma unroll
        for (int g = 0; g < 3; ++g) {
            pn[t][g] = P[g * 128 + n];
            bi[t][g] = bih[g * 128 + n];
            bh[t][g] = bhh[g * 128 + n];
        }
    }
#pragma unroll
    for (int sub = 0; sub < 2; ++sub)
#pragma unroll
        for (int r = 0; r < 4; ++r) {
            int a = abase + sub * 16 + q * 4 + r;
            deg[sub][r] = (a < N) ? (float)(rowptr[a + 1] - rowptr[a]) : 0.f;
        }

    {
        int a = tid >> 3, ch = tid & 7;
        int aa = abase + a; if (aa >= N) aa = N - 1;
        const uint4* src = (const uint4*)(Sbf + (size_t)aa * HH + ch * 16);
        uint4 v0 = src[0];
        uint4 v1 = src[1];
        uint4* dst = (uint4*)&Sb[a][ch * 16];
        dst[0] = v0;
        dst[1] = v1;
    }
    __syncthreads();

    floatx4 Cg[3][2][2];
#pragma unroll
    for (int g = 0; g < 3; ++g)
#pragma unroll
        for (int t = 0; t < 2; ++t)
#pragma unroll
            for (int sub = 0; sub < 2; ++sub)
                Cg[g][t][sub] = floatx4{0.f, 0.f, 0.f, 0.f};

#pragma unroll
    for (int kt = 0; kt < 4; ++kt) {
        short8 A0 = *(const short8*)&Sb[c][kt * 32 + q * 8];
        short8 A1 = *(const short8*)&Sb[16 + c][kt * 32 + q * 8];
#pragma unroll
        for (int g = 0; g < 3; ++g)
#pragma unroll
            for (int t = 0; t < 2; ++t) {
                int nrow = g * 128 + w * 32 + t * 16 + c;
                short8 B = *(const short8*)&WcT[(size_t)nrow * HH + kt * 32 + q * 8];
                Cg[g][t][0] = __builtin_amdgcn_mfma_f32_16x16x32_bf16(A0, B, Cg[g][t][0], 0, 0, 0);
                Cg[g][t][1] = __builtin_amdgcn_mfma_f32_16x16x32_bf16(A1, B, Cg[g][t][1], 0, 0, 0);
            }
    }

#pragma unroll
    for (int sub = 0; sub < 2; ++sub)
#pragma unroll
        for (int r = 0; r < 4; ++r) {
            int am = sub * 16 + q * 4 + r;
            int a = abase + am;
            bool ok = a < N;
#pragma unroll
            for (int t = 0; t < 2; ++t) {
                int n = w * 32 + t * 16 + c;
                float g0 = Cg[0][t][sub][r] + deg[sub][r] * pn[t][0] + bi[t][0];
                float g1 = Cg[1][t][sub][r] + deg[sub][r] * pn[t][1] + bi[t][1];
                float g2 = Cg[2][t][sub][r] + deg[sub][r] * pn[t][2] + bi[t][2];
                float rr = fast_sigmoid(g0 + bh[t][0]);
                float zz = fast_sigmoid(g1 + bh[t][1]);
                float nn = fast_tanh(g2 + rr * bh[t][2]);
                float xv = 0.f;
                if (ok) {
                    xv = X[(size_t)a * HH + n] + (1.f - zz) * nn;
                    X[(size_t)a * HH + n] = xv;
                }
                Xb[am][n] = f2bf(xv);
            }
        }

    if (!do_xw) return;
    __syncthreads();

    floatx4 Cx[2][2];
#pragma unroll
    for (int t = 0; t < 2; ++t)
#pragma unroll
        for (int sub = 0; sub < 2; ++sub)
            Cx[t][sub] = floatx4{0.f, 0.f, 0.f, 0.f};
#pragma unroll
    for (int kt = 0; kt < 4; ++kt) {
        short8 A0 = *(const short8*)&Xb[c][kt * 32 + q * 8];
        short8 A1 = *(const short8*)&Xb[16 + c][kt * 32 + q * 8];
#pragma unroll
        for (int t = 0; t < 2; ++t) {
            int nrow = w * 32 + t * 16 + c;
            short8 B = *(const short8*)&W1xT[(size_t)nrow * HH + kt * 32 + q * 8];
            Cx[t][0] = __builtin_amdgcn_mfma_f32_16x16x32_bf16(A0, B, Cx[t][0], 0, 0, 0);
            Cx[t][1] = __builtin_amdgcn_mfma_f32_16x16x32_bf16(A1, B, Cx[t][1], 0, 0, 0);
        }
    }
#pragma unroll
    for (int sub = 0; sub < 2; ++sub)
#pragma unroll
        for (int r = 0; r < 4; ++r) {
            int a = abase + sub * 16 + q * 4 + r;
            if (a >= N) continue;
#pragma unroll
            for (int t = 0; t < 2; ++t) {
                int n = w * 32 + t * 16 + c;
                XWb[(size_t)a * HH + n] = f2bf(Cx[t][sub][r] + b1next[n]);
            }
        }
}

// Fused LayerNorm + mean-pool: block per molecule (sorted batch segments).
__global__ __launch_bounds__(1024) void lnpool_kernel(
    const float* __restrict__ X, const float* __restrict__ g,
    const float* __restrict__ b, const int* __restrict__ bptr,
    float* __restrict__ outx, float* __restrict__ outg, int N)
{
    __shared__ float sm[16][128];
    int m = blockIdx.x, tid = threadIdx.x;
    int wv = tid >> 6, lane = tid & 63;
    int a0 = bptr[m], a1 = bptr[m + 1];
    float g0 = g[lane], g1 = g[64 + lane];
    float bb0 = b[lane], bb1 = b[64 + lane];
    float acc0 = 0.f, acc1 = 0.f;
    for (int a = a0 + wv; a < a1; a += 16) {
        float v0 = X[(size_t)a * HH + lane];
        float v1 = X[(size_t)a * HH + 64 + lane];
        float smv = v0 + v1;
        for (int off = 32; off > 0; off >>= 1) smv += __shfl_xor(smv, off, 64);
        float mu = smv * (1.f / 128.f);
        float d0 = v0 - mu, d1 = v1 - mu;
        float vq = d0 * d0 + d1 * d1;
        for (int off = 32; off > 0; off >>= 1) vq += __shfl_xor(vq, off, 64);
        float inv = rsqrtf(vq * (1.f / 128.f) + 1e-5f);
        float y0 = d0 * inv * g0 + bb0;
        float y1 = d1 * inv * g1 + bb1;
        outx[(size_t)a * HH + lane] = y0;
        outx[(size_t)a * HH + 64 + lane] = y1;
        acc0 += y0;
        acc1 += y1;
    }
    sm[wv][lane] = acc0;
    sm[wv][64 + lane] = acc1;
    __syncthreads();
    if (tid < 128) {
        float s = 0.f;
#pragma unroll
        for (int i = 0; i < 16; ++i) s += sm[i][tid];
        float cnt = (float)(a1 - a0);
        outg[(size_t)m * HH + tid] = s / fmaxf(cnt, 1.f);
    }
}

extern "C" void kernel_launch(void* const* d_in, const int* in_sizes, int n_in,
                              void* d_out, int out_size, void* d_ws, size_t ws_size,
                              hipStream_t stream)
{
    const int*   an   = (const int*)d_in[0];
    const float* pos  = (const float*)d_in[1];
    const int*   bat  = (const int*)d_in[2];
    const int*   eidx = (const int*)d_in[3];
    const float* emb  = (const float*)d_in[4];
    const float* W1   = (const float*)d_in[5];
    const float* b1   = (const float*)d_in[6];
    const float* W2   = (const float*)d_in[7];
    const float* b2   = (const float*)d_in[8];
    const float* Wih  = (const float*)d_in[9];
    const float* bih  = (const float*)d_in[10];
    const float* bhh  = (const float*)d_in[11];
    const float* lng  = (const float*)d_in[12];
    const float* lnb  = (const float*)d_in[13];

    int N = in_sizes[0];
    int E = in_sizes[3] / 2;
    int M = out_size / HH - N;
    const int* erow = eidx;
    const int* ecol = eidx + E;

    float* ws   = (float*)d_ws;
    size_t off = 0;
    float* X    = ws + off; off += (size_t)N * HH;
    unsigned short* Sbf = (unsigned short*)(ws + off); off += (size_t)N * HH / 2;
    unsigned short* XWb = (unsigned short*)(ws + off); off += (size_t)N * HH / 2;
    float* P    = ws + off; off += LL * 384;
    float* dist = ws + off; off += E;
    int* rowptr = (int*)(ws + off); off += N + 1;
    int* bptr   = (int*)(ws + off); off += M + 1;
    off = (off + 3) & ~(size_t)3;
    unsigned short* W1rT = (unsigned short*)(ws + off); off += (size_t)LL * HH * 32;
    unsigned short* W1xT = (unsigned short*)(ws + off); off += (size_t)LL * HH * 64;
    unsigned short* WcT  = (unsigned short*)(ws + off); off += (size_t)LL * 384 * 64;

    float* outx = (float*)d_out;
    float* outg = outx + (size_t)N * HH;

    int PT = (E > N ? E : N);
    long total = (long)N * HH + PT + E + LL * HH * 64 + LL * HH * HH
               + LL * HH * 384 + LL * 384;
    int prep_blocks = (int)((total + 255) / 256);

    prep_kernel<<<prep_blocks, 256, 0, stream>>>(
        an, emb, X, pos, erow, ecol, dist, rowptr, bptr, bat,
        W1, W1rT, W1xT, W2, Wih, WcT, b2, P, N, E, M);

    xw_kernel<<<(N + XAB - 1) / XAB, 256, 0, stream>>>(X, W1, b1, XWb, N);

    int eblocks = (2 * N + 3) / 4;       // one (atom, half) per wave
    int nwaves = eblocks * 4;
    int grux_blocks = (N + GA - 1) / GA;
    for (int l = 0; l < LL; ++l) {
        edge_mfma_kernel<<<eblocks, 256, 0, stream>>>(
            XWb, W1rT + (size_t)l * HH * 64, dist, rowptr, ecol, Sbf, N, nwaves);
        int do_xw = (l < LL - 1) ? 1 : 0;
        int ln = (l + 1 < LL) ? l + 1 : l;
        grux_mfma_kernel<<<grux_blocks, 256, 0, stream>>>(
            Sbf, WcT + (size_t)l * 384 * HH, P + l * 384,
            bih + l * 384, bhh + l * 384, rowptr, X, N,
            W1xT + (size_t)ln * HH * HH, b1 + (size_t)ln * HH, XWb, do_xw);
    }

    lnpool_kernel<<<M, 1024, 0, stream>>>(X, lng, lnb, bptr, outx, outg, N);
}